// Round 1
// baseline (701.358 us; speedup 1.0000x reference)
//
#include <hip/hip_runtime.h>

#define B_ 4
#define T_ 2048
#define C_ 1024
#define H_ 16
#define DK_ 64
#define BT_ 8192

using u16 = unsigned short;
using u32 = unsigned int;
using u64 = unsigned long long;
typedef __attribute__((ext_vector_type(8))) short short8;
typedef __attribute__((ext_vector_type(4))) float f32x4;

__device__ __forceinline__ u16 f2bf(float f) {
  u32 u = __builtin_bit_cast(u32, f);
  u32 r = u + 0x7fffu + ((u >> 16) & 1u);
  return (u16)(r >> 16);
}

__device__ __forceinline__ void glds16(void* lds, const void* g) {
  __builtin_amdgcn_global_load_lds(
      (__attribute__((address_space(1))) u32*)g,
      (__attribute__((address_space(3))) u32*)lds, 16, 0, 0);
}

// ---------------- fp32 -> bf16 conversion (vectorized, grid-stride) ---------
__global__ void cvt_bf16_k(const float* __restrict__ s, u16* __restrict__ d, int n) {
  int i0 = (blockIdx.x * blockDim.x + threadIdx.x) * 4;
  int stride = gridDim.x * blockDim.x * 4;
  for (int i = i0; i < n; i += stride) {
    float4 v = *(const float4*)(s + i);
    u64 p = (u64)f2bf(v.x) | ((u64)f2bf(v.y) << 16) |
            ((u64)f2bf(v.z) << 32) | ((u64)f2bf(v.w) << 48);
    *(u64*)(d + i) = p;
  }
}

// ---------------- mask int32 -> bitmask (1 bit per entry) -------------------
__global__ void mask_bits_k(const int* __restrict__ m, u64* __restrict__ out, int nw) {
  int w0 = blockIdx.x * (blockDim.x >> 6) + (threadIdx.x >> 6);
  int lane = threadIdx.x & 63;
  int stride = gridDim.x * (blockDim.x >> 6);
  for (int w = w0; w < nw; w += stride) {
    int v = m[(size_t)w * 64 + lane];
    u64 bits = __ballot(v != 0);
    if (lane == 0) out[w] = bits;
  }
}

// ---------------- NT GEMM, 128x128 tile, bf16 MFMA (m97 structure) ----------
// C[m][n] = sum_k A[m][k] * Bmat[n][k] (+ bias), epilogue per MODE:
//   MODE 0: bf16 out, head layout [B,H,T,DK], bias[n]
//   MODE 1: bf16 out, row-major [M][N] (V^T path, A=Wv), bias[m]
//   MODE 2: f32 out, row-major [M][N], bias[n]
template <int MODE>
__global__ __launch_bounds__(256) void gemm_nt(
    const u16* __restrict__ A, const u16* __restrict__ Bmat,
    const float* __restrict__ bias, void* __restrict__ out,
    int M, int N, int K) {
  __shared__ __align__(16) u16 As[128 * 32];
  __shared__ __align__(16) u16 Bs[128 * 32];
  const int t = threadIdx.x;
  const int lane = t & 63;
  const int wave = t >> 6;
  const int wr = wave >> 1, wc = wave & 1;
  const int lr = lane & 15, lg = lane >> 4;
  const int m0 = blockIdx.x * 128;
  const int n0 = blockIdx.y * 128;

  f32x4 acc[4][4] = {};

  const int srow = t >> 2;
  const int scol = (t & 3) * 8;
  const u16* ag = A + (size_t)(m0 + srow) * K + scol;
  const u16* bg = Bmat + (size_t)(n0 + srow) * K + scol;
  u16* as0 = &As[srow * 32 + scol];
  u16* as1 = &As[(srow + 64) * 32 + scol];
  u16* bs0 = &Bs[srow * 32 + scol];
  u16* bs1 = &Bs[(srow + 64) * 32 + scol];

  for (int k0 = 0; k0 < K; k0 += 32) {
    glds16(as0, ag + k0);
    glds16(as1, ag + (size_t)64 * K + k0);
    glds16(bs0, bg + k0);
    glds16(bs1, bg + (size_t)64 * K + k0);
    __syncthreads();
    short8 af[4], bf[4];
#pragma unroll
    for (int m = 0; m < 4; ++m)
      af[m] = *(const short8*)&As[(wr * 64 + m * 16 + lr) * 32 + lg * 8];
#pragma unroll
    for (int n = 0; n < 4; ++n)
      bf[n] = *(const short8*)&Bs[(wc * 64 + n * 16 + lr) * 32 + lg * 8];
#pragma unroll
    for (int m = 0; m < 4; ++m)
#pragma unroll
      for (int n = 0; n < 4; ++n)
        acc[m][n] = __builtin_amdgcn_mfma_f32_16x16x32_bf16(af[m], bf[n], acc[m][n], 0, 0, 0);
    __syncthreads();
  }

#pragma unroll
  for (int m = 0; m < 4; ++m) {
#pragma unroll
    for (int n = 0; n < 4; ++n) {
#pragma unroll
      for (int j = 0; j < 4; ++j) {
        const int gm = m0 + wr * 64 + m * 16 + lg * 4 + j;
        const int gn = n0 + wc * 64 + n * 16 + lr;
        float v = acc[m][n][j];
        if (MODE == 0) {
          v += bias[gn];
          const int b = gm >> 11, tt = gm & 2047, h = gn >> 6, d = gn & 63;
          ((u16*)out)[((((size_t)b * H_ + h) * T_ + tt) << 6) + d] = f2bf(v);
        } else if (MODE == 1) {
          v += bias[gm];
          ((u16*)out)[(size_t)gm * N + gn] = f2bf(v);
        } else {
          v += bias[gn];
          ((float*)out)[(size_t)gm * N + gn] = v;
        }
      }
    }
  }
}

// ---------------- masked flash attention ------------------------------------
// Qh,Kh: [B,H,T,64] bf16.  Vt: [H*64][B*T] bf16 (row = h*64+d, col = b*T+t).
// mb: [B,T,T/64] bitmask.  Y: [B,T,C] bf16.
__global__ __launch_bounds__(256) void attn_k(
    const u16* __restrict__ Qh, const u16* __restrict__ Kh,
    const u16* __restrict__ Vt, const u64* __restrict__ mb,
    u16* __restrict__ Y) {
  __shared__ __align__(16) u16 Plds[4][16][32];
  const int bh = blockIdx.y;
  const int b = bh >> 4, h = bh & 15;
  const int wave = threadIdx.x >> 6, lane = threadIdx.x & 63;
  const int lr = lane & 15, lg = lane >> 4;
  const int q0 = blockIdx.x * 64 + wave * 16;

  const u16* Qb = Qh + ((size_t)bh * T_ + q0) * DK_;
  const u16* Kb = Kh + (size_t)bh * T_ * DK_;
  const u16* Vb = Vt + (size_t)h * DK_ * BT_ + (size_t)b * T_;

  const short8 qf0 = *(const short8*)(Qb + lr * DK_ + lg * 8);
  const short8 qf1 = *(const short8*)(Qb + lr * DK_ + 32 + lg * 8);

  const u64* mr[4];
#pragma unroll
  for (int j = 0; j < 4; ++j)
    mr[j] = mb + ((size_t)b * T_ + q0 + lg * 4 + j) * (T_ / 64);

  float m_r[4] = {-1e30f, -1e30f, -1e30f, -1e30f};
  float l_r[4] = {0.f, 0.f, 0.f, 0.f};
  f32x4 yacc[4] = {{0,0,0,0},{0,0,0,0},{0,0,0,0},{0,0,0,0}};

  for (int kv = 0; kv < T_; kv += 32) {
    f32x4 st[2];
#pragma unroll
    for (int kt = 0; kt < 2; ++kt) {
      const u16* Kt = Kb + (size_t)(kv + kt * 16 + lr) * DK_ + lg * 8;
      const short8 kf0 = *(const short8*)(Kt);
      const short8 kf1 = *(const short8*)(Kt + 32);
      f32x4 z = {0.f, 0.f, 0.f, 0.f};
      z = __builtin_amdgcn_mfma_f32_16x16x32_bf16(qf0, kf0, z, 0, 0, 0);
      z = __builtin_amdgcn_mfma_f32_16x16x32_bf16(qf1, kf1, z, 0, 0, 0);
      st[kt] = z;
    }
    const int word = kv >> 6;
    const int bb = kv & 32;
#pragma unroll
    for (int j = 0; j < 4; ++j) {
      const u64 mw = mr[j][word];
#pragma unroll
      for (int kt = 0; kt < 2; ++kt) {
        const float s = st[kt][j] * 0.125f;
        st[kt][j] = ((mw >> (bb + kt * 16 + lr)) & 1) ? s : -1e9f;
      }
    }
#pragma unroll
    for (int j = 0; j < 4; ++j) {
      float mx = fmaxf(st[0][j], st[1][j]);
      mx = fmaxf(mx, __shfl_xor(mx, 1));
      mx = fmaxf(mx, __shfl_xor(mx, 2));
      mx = fmaxf(mx, __shfl_xor(mx, 4));
      mx = fmaxf(mx, __shfl_xor(mx, 8));
      const float mn = fmaxf(m_r[j], mx);
      const float al = __expf(m_r[j] - mn);
      m_r[j] = mn;
      const float p0 = __expf(st[0][j] - mn);
      const float p1 = __expf(st[1][j] - mn);
      float rs = p0 + p1;
      rs += __shfl_xor(rs, 1);
      rs += __shfl_xor(rs, 2);
      rs += __shfl_xor(rs, 4);
      rs += __shfl_xor(rs, 8);
      l_r[j] = l_r[j] * al + rs;
#pragma unroll
      for (int n = 0; n < 4; ++n) yacc[n][j] *= al;
      Plds[wave][lg * 4 + j][lr] = f2bf(p0);
      Plds[wave][lg * 4 + j][16 + lr] = f2bf(p1);
    }
    const short8 pa = *(const short8*)&Plds[wave][lr][lg * 8];
#pragma unroll
    for (int n = 0; n < 4; ++n) {
      const u16* vp = Vb + (size_t)(n * 16 + lr) * BT_ + kv + lg * 8;
      const short8 vf = *(const short8*)(vp);
      yacc[n] = __builtin_amdgcn_mfma_f32_16x16x32_bf16(pa, vf, yacc[n], 0, 0, 0);
    }
  }
#pragma unroll
  for (int j = 0; j < 4; ++j) {
    const float inv = 1.0f / l_r[j];
    const size_t row = (size_t)b * T_ + q0 + lg * 4 + j;
#pragma unroll
    for (int n = 0; n < 4; ++n)
      Y[row * C_ + h * DK_ + n * 16 + lr] = f2bf(yacc[n][j] * inv);
  }
}

// ---------------------------------------------------------------------------
extern "C" void kernel_launch(void* const* d_in, const int* in_sizes, int n_in,
                              void* d_out, int out_size, void* d_ws, size_t ws_size,
                              hipStream_t stream) {
  const float* q  = (const float*)d_in[0];
  const float* k  = (const float*)d_in[1];
  const float* v  = (const float*)d_in[2];
  const int* mask = (const int*)d_in[3];
  const float* Wq = (const float*)d_in[4];
  const float* bq = (const float*)d_in[5];
  const float* Wk = (const float*)d_in[6];
  const float* bk = (const float*)d_in[7];
  const float* Wv = (const float*)d_in[8];
  const float* bv = (const float*)d_in[9];
  const float* Wf = (const float*)d_in[10];
  const float* bf = (const float*)d_in[11];
  float* out = (float*)d_out;
  char* ws = (char*)d_ws;

  size_t off = 0;
  auto nxt = [&](size_t bytes) -> void* {
    void* p = ws + off;
    off += (bytes + 255) & ~(size_t)255;
    return p;
  };
  const size_t big = (size_t)BT_ * C_ * 2;   // 16 MB
  const size_t wsz = (size_t)C_ * C_ * 2;    // 2 MB
  u16* qb  = (u16*)nxt(big);
  u16* kb  = (u16*)nxt(big);
  u16* vb  = (u16*)nxt(big);
  u16* Wqb = (u16*)nxt(wsz);
  u16* Wkb = (u16*)nxt(wsz);
  u16* Wvb = (u16*)nxt(wsz);
  u16* Wfb = (u16*)nxt(wsz);
  u16* Qh  = (u16*)nxt(big);
  u16* Kh  = (u16*)nxt(big);
  u16* Vt  = (u16*)nxt(big);
  u16* Yb  = (u16*)nxt(big);
  u64* mb  = (u64*)nxt((size_t)B_ * T_ * (T_ / 64) * 8);

  // conversions
  cvt_bf16_k<<<2048, 256, 0, stream>>>(q, qb, BT_ * C_);
  cvt_bf16_k<<<2048, 256, 0, stream>>>(k, kb, BT_ * C_);
  cvt_bf16_k<<<2048, 256, 0, stream>>>(v, vb, BT_ * C_);
  cvt_bf16_k<<<512, 256, 0, stream>>>(Wq, Wqb, C_ * C_);
  cvt_bf16_k<<<512, 256, 0, stream>>>(Wk, Wkb, C_ * C_);
  cvt_bf16_k<<<512, 256, 0, stream>>>(Wv, Wvb, C_ * C_);
  cvt_bf16_k<<<512, 256, 0, stream>>>(Wf, Wfb, C_ * C_);
  mask_bits_k<<<2048, 256, 0, stream>>>(mask, mb, B_ * T_ * T_ / 64);

  // projections: Q, K -> [B,H,T,DK]
  gemm_nt<0><<<dim3(BT_ / 128, C_ / 128), 256, 0, stream>>>(qb, Wqb, bq, Qh, BT_, C_, C_);
  gemm_nt<0><<<dim3(BT_ / 128, C_ / 128), 256, 0, stream>>>(kb, Wkb, bk, Kh, BT_, C_, C_);
  // V transposed: Vt[h*64+d][b*T+t]  (A = Wv, B = vb)
  gemm_nt<1><<<dim3(C_ / 128, BT_ / 128), 256, 0, stream>>>(Wvb, vb, bv, Vt, C_, BT_, C_);

  // attention
  attn_k<<<dim3(T_ / 64, B_ * H_), 256, 0, stream>>>(Qh, Kh, Vt, mb, Yb);

  // output projection -> f32 d_out
  gemm_nt<2><<<dim3(BT_ / 128, C_ / 128), 256, 0, stream>>>(Yb, Wfb, bf, out, BT_, C_, C_);
}

// Round 3
// 543.730 us; speedup vs baseline: 1.2899x; 1.2899x over previous
//
#include <hip/hip_runtime.h>

#define B_ 4
#define T_ 2048
#define C_ 1024
#define H_ 16
#define DK_ 64
#define BT_ 8192

using u16 = unsigned short;
using u32 = unsigned int;
using u64 = unsigned long long;
typedef __attribute__((ext_vector_type(8))) short short8;
typedef __attribute__((ext_vector_type(4))) float f32x4;
typedef __attribute__((ext_vector_type(16))) float f32x16;
typedef __attribute__((ext_vector_type(4))) u32 u32x4;
typedef __attribute__((ext_vector_type(2))) u32 u32x2;

__device__ __forceinline__ u16 f2bf(float f) {
  u32 u = __builtin_bit_cast(u32, f);
  u32 r = u + 0x7fffu + ((u >> 16) & 1u);
  return (u16)(r >> 16);
}

__device__ __forceinline__ void glds16(void* lds, const void* g) {
  __builtin_amdgcn_global_load_lds(
      (__attribute__((address_space(1))) u32*)g,
      (__attribute__((address_space(3))) u32*)lds, 16, 0, 0);
}

// ---------------- fp32 -> bf16 conversion (vectorized, grid-stride) ---------
__global__ void cvt_bf16_k(const float* __restrict__ s, u16* __restrict__ d, int n) {
  int i0 = (blockIdx.x * blockDim.x + threadIdx.x) * 4;
  int stride = gridDim.x * blockDim.x * 4;
  for (int i = i0; i < n; i += stride) {
    float4 v = *(const float4*)(s + i);
    u64 p = (u64)f2bf(v.x) | ((u64)f2bf(v.y) << 16) |
            ((u64)f2bf(v.z) << 32) | ((u64)f2bf(v.w) << 48);
    *(u64*)(d + i) = p;
  }
}

// ---------------- mask int32 -> bitmask (1 bit per entry) -------------------
__global__ void mask_bits_k(const int* __restrict__ m, u64* __restrict__ out, int nw) {
  int w0 = blockIdx.x * (blockDim.x >> 6) + (threadIdx.x >> 6);
  int lane = threadIdx.x & 63;
  int stride = gridDim.x * (blockDim.x >> 6);
  for (int w = w0; w < nw; w += stride) {
    int v = m[(size_t)w * 64 + lane];
    u64 bits = __ballot(v != 0);
    if (lane == 0) out[w] = bits;
  }
}

// ---------------- NT GEMM, 128x128 tile, bf16 MFMA (m97 structure) ----------
// C[m][n] = (sum_k A[m][k]*Bmat[n][k] + bias) * scale, epilogue per MODE:
//   MODE 0: bf16 out, head layout [B,H,T,DK], bias[n]
//   MODE 1: bf16 out, row-major [M][N] (V^T path, A=Wv), bias[m]
//   MODE 2: f32 out, row-major [M][N], bias[n]
template <int MODE>
__global__ __launch_bounds__(256) void gemm_nt(
    const u16* __restrict__ A, const u16* __restrict__ Bmat,
    const float* __restrict__ bias, void* __restrict__ out,
    int M, int N, int K, float scale) {
  __shared__ __align__(16) u16 As[128 * 32];
  __shared__ __align__(16) u16 Bs[128 * 32];
  const int t = threadIdx.x;
  const int lane = t & 63;
  const int wave = t >> 6;
  const int wr = wave >> 1, wc = wave & 1;
  const int lr = lane & 15, lg = lane >> 4;
  const int m0 = blockIdx.x * 128;
  const int n0 = blockIdx.y * 128;

  f32x4 acc[4][4] = {};

  const int srow = t >> 2;
  const int scol = (t & 3) * 8;
  const u16* ag = A + (size_t)(m0 + srow) * K + scol;
  const u16* bg = Bmat + (size_t)(n0 + srow) * K + scol;
  u16* as0 = &As[srow * 32 + scol];
  u16* as1 = &As[(srow + 64) * 32 + scol];
  u16* bs0 = &Bs[srow * 32 + scol];
  u16* bs1 = &Bs[(srow + 64) * 32 + scol];

  for (int k0 = 0; k0 < K; k0 += 32) {
    glds16(as0, ag + k0);
    glds16(as1, ag + (size_t)64 * K + k0);
    glds16(bs0, bg + k0);
    glds16(bs1, bg + (size_t)64 * K + k0);
    __syncthreads();
    short8 af[4], bf[4];
#pragma unroll
    for (int m = 0; m < 4; ++m)
      af[m] = *(const short8*)&As[(wr * 64 + m * 16 + lr) * 32 + lg * 8];
#pragma unroll
    for (int n = 0; n < 4; ++n)
      bf[n] = *(const short8*)&Bs[(wc * 64 + n * 16 + lr) * 32 + lg * 8];
#pragma unroll
    for (int m = 0; m < 4; ++m)
#pragma unroll
      for (int n = 0; n < 4; ++n)
        acc[m][n] = __builtin_amdgcn_mfma_f32_16x16x32_bf16(af[m], bf[n], acc[m][n], 0, 0, 0);
    __syncthreads();
  }

#pragma unroll
  for (int m = 0; m < 4; ++m) {
#pragma unroll
    for (int n = 0; n < 4; ++n) {
#pragma unroll
      for (int j = 0; j < 4; ++j) {
        const int gm = m0 + wr * 64 + m * 16 + lg * 4 + j;
        const int gn = n0 + wc * 64 + n * 16 + lr;
        float v = acc[m][n][j];
        if (MODE == 0) {
          v = (v + bias[gn]) * scale;
          const int b = gm >> 11, tt = gm & 2047, h = gn >> 6, d = gn & 63;
          ((u16*)out)[((((size_t)b * H_ + h) * T_ + tt) << 6) + d] = f2bf(v);
        } else if (MODE == 1) {
          v += bias[gm];
          ((u16*)out)[(size_t)gm * N + gn] = f2bf(v);
        } else {
          v += bias[gn];
          ((float*)out)[(size_t)gm * N + gn] = v;
        }
      }
    }
  }
}

// ---------------- masked flash attention, swapped-QK^T 32x32, no LDS --------
// Qh: [B,H,T,64] bf16, pre-scaled by 0.125*log2(e).  Kh: [B,H,T,64] bf16.
// Vt: [H*64][B*T] bf16.  mb: [B,T,T/64] bitmask.  Y: [B,T,C] bf16.
// 4 waves/block, 32 q-rows/wave, KV step 64. exp2-domain online softmax.
// PV uses a relabeled contraction sigma(k) = (k&3)+8*((k&7)>>2)+4*(k>>3) so
// the P fragment packs IN-LANE (no cross-lane ops); V loads follow sigma.
__global__ __launch_bounds__(256) void attn32_k(
    const u16* __restrict__ Qh, const u16* __restrict__ Kh,
    const u16* __restrict__ Vt, const u64* __restrict__ mb,
    u16* __restrict__ Y) {
  // XCD-bijective remap: 1024 blocks, 128 consecutive logical ids per XCD
  const int f = blockIdx.x;
  const int lgid = ((f & 7) << 7) | (f >> 3);
  const int bh = lgid >> 4, qblk = lgid & 15;
  const int b = bh >> 4, h = bh & 15;
  const int wave = threadIdx.x >> 6, lane = threadIdx.x & 63;
  const int lq = lane & 31, hi = lane >> 5;
  const int q0 = qblk * 128 + wave * 32;

  // Q B-fragments: lane holds Q[q0+lq][kt*16 + 8*hi .. +7]
  const u16* Qp = Qh + ((size_t)bh * T_ + q0 + lq) * DK_ + hi * 8;
  short8 qf[4];
#pragma unroll
  for (int kt = 0; kt < 4; ++kt) qf[kt] = *(const short8*)(Qp + kt * 16);

  const u16* Kp = Kh + ((size_t)bh * T_ + lq) * DK_ + hi * 8;
  const u16* Vp = Vt + ((size_t)(h * DK_ + lq)) * BT_ + (size_t)b * T_ + hi * 4;
  const u64* mrow = mb + ((size_t)b * T_ + q0 + lq) * (T_ / 64);

  float m_run = -3.0e38f, l_run = 0.f;
  f32x16 o0 = {}, o1 = {};

  for (int kv = 0; kv < T_; kv += 64) {
    const u64 mw = mrow[kv >> 6] >> (hi * 4);
    const u32 mlo = (u32)mw, mhi2 = (u32)(mw >> 32);

    // S^T = K * Q^T : lane owns q = lq, kv rows (r&3)+8*(r>>2)+4*hi (+32 in c1)
    f32x16 c0 = {}, c1 = {};
    __builtin_amdgcn_s_setprio(1);
#pragma unroll
    for (int kt = 0; kt < 4; ++kt) {
      const short8 k0 = *(const short8*)(Kp + (size_t)kv * DK_ + kt * 16);
      const short8 k1 = *(const short8*)(Kp + (size_t)(kv + 32) * DK_ + kt * 16);
      c0 = __builtin_amdgcn_mfma_f32_32x32x16_bf16(k0, qf[kt], c0, 0, 0, 0);
      c1 = __builtin_amdgcn_mfma_f32_32x32x16_bf16(k1, qf[kt], c1, 0, 0, 0);
    }
    __builtin_amdgcn_s_setprio(0);

    float s0[16], s1[16];
#pragma unroll
    for (int r = 0; r < 16; ++r) {
      const int pos = (r & 3) + 8 * (r >> 2);
      s0[r] = ((mlo >> pos) & 1u) ? c0[r] : -1e9f;
      s1[r] = ((mhi2 >> pos) & 1u) ? c1[r] : -1e9f;
    }
    // in-register row max (tree) + pair merge across lane^32
    float mx[8];
#pragma unroll
    for (int r = 0; r < 8; ++r)
      mx[r] = fmaxf(fmaxf(s0[r], s0[r + 8]), fmaxf(s1[r], s1[r + 8]));
#pragma unroll
    for (int d = 4; d; d >>= 1)
#pragma unroll
      for (int r = 0; r < d; ++r) mx[r] = fmaxf(mx[r], mx[r + d]);
    const float pmax = fmaxf(mx[0], __shfl_xor(mx[0], 32));

    // defer-max (T13): only rescale when max grew past threshold
    if (!__all(pmax <= m_run + 8.0f)) {
      const float mnew = fmaxf(m_run, pmax);
      const float al = __builtin_amdgcn_exp2f(m_run - mnew);
      m_run = mnew;
      l_run *= al;
#pragma unroll
      for (int r = 0; r < 16; ++r) {
        const int row = (r & 3) + 8 * (r >> 2) + 4 * hi;
        const float alr = __shfl(al, row);
        o0[r] *= alr;
        o1[r] *= alr;
      }
    }

#pragma unroll
    for (int r = 0; r < 16; ++r) {
      s0[r] = __builtin_amdgcn_exp2f(s0[r] - m_run);
      s1[r] = __builtin_amdgcn_exp2f(s1[r] - m_run);
    }
    float sm[8];
#pragma unroll
    for (int r = 0; r < 8; ++r)
      sm[r] = (s0[r] + s0[r + 8]) + (s1[r] + s1[r + 8]);
#pragma unroll
    for (int d = 4; d; d >>= 1)
#pragma unroll
      for (int r = 0; r < d; ++r) sm[r] += sm[r + d];
    l_run += sm[0] + __shfl_xor(sm[0], 32);

    // P -> bf16 PV A-fragments, IN-LANE pack (relabeled contraction):
    // fragment g covers kv block [kv+16g, kv+16g+16); element e of lane-half
    // hi holds P at kv-local sigma = 4*hi + (e&3) + 8*(e>>2), which is s-reg
    // r = e (+8 for odd g) of s0 (g<2) / s1 (g>=2).
    u32 pw_[4][4];
#pragma unroll
    for (int g = 0; g < 4; ++g) {
      const float* pe = (g < 2) ? s0 : s1;
      const int ob = (g & 1) * 8;
#pragma unroll
      for (int w2 = 0; w2 < 4; ++w2)
        pw_[g][w2] = (u32)f2bf(pe[ob + 2 * w2]) |
                     ((u32)f2bf(pe[ob + 2 * w2 + 1]) << 16);
    }
    __builtin_amdgcn_s_setprio(1);
#pragma unroll
    for (int g = 0; g < 4; ++g) {
      const u16* vp = Vp + (size_t)(kv + g * 16);
      const u32x2 l0 = *(const u32x2*)(vp);
      const u32x2 l1 = *(const u32x2*)(vp + 8);
      const u32x2 n0v = *(const u32x2*)(vp + (size_t)32 * BT_);
      const u32x2 n1v = *(const u32x2*)(vp + (size_t)32 * BT_ + 8);
      const u32x4 pu = {pw_[g][0], pw_[g][1], pw_[g][2], pw_[g][3]};
      const u32x4 v0u = {l0[0], l0[1], l1[0], l1[1]};
      const u32x4 v1u = {n0v[0], n0v[1], n1v[0], n1v[1]};
      const short8 pa = __builtin_bit_cast(short8, pu);
      o0 = __builtin_amdgcn_mfma_f32_32x32x16_bf16(pa, __builtin_bit_cast(short8, v0u), o0, 0, 0, 0);
      o1 = __builtin_amdgcn_mfma_f32_32x32x16_bf16(pa, __builtin_bit_cast(short8, v1u), o1, 0, 0, 0);
    }
    __builtin_amdgcn_s_setprio(0);
  }

  const float linv = 1.0f / l_run;
#pragma unroll
  for (int r = 0; r < 16; ++r) {
    const int row = (r & 3) + 8 * (r >> 2) + 4 * hi;
    const float li = __shfl(linv, row);
    u16* yp = Y + ((size_t)b * T_ + q0 + row) * C_ + h * DK_ + lq;
    yp[0] = f2bf(o0[r] * li);
    yp[32] = f2bf(o1[r] * li);
  }
}

// ---------------------------------------------------------------------------
extern "C" void kernel_launch(void* const* d_in, const int* in_sizes, int n_in,
                              void* d_out, int out_size, void* d_ws, size_t ws_size,
                              hipStream_t stream) {
  const float* q  = (const float*)d_in[0];
  const float* k  = (const float*)d_in[1];
  const float* v  = (const float*)d_in[2];
  const int* mask = (const int*)d_in[3];
  const float* Wq = (const float*)d_in[4];
  const float* bq = (const float*)d_in[5];
  const float* Wk = (const float*)d_in[6];
  const float* bk = (const float*)d_in[7];
  const float* Wv = (const float*)d_in[8];
  const float* bv = (const float*)d_in[9];
  const float* Wf = (const float*)d_in[10];
  const float* bf = (const float*)d_in[11];
  float* out = (float*)d_out;
  char* ws = (char*)d_ws;

  size_t off = 0;
  auto nxt = [&](size_t bytes) -> void* {
    void* p = ws + off;
    off += (bytes + 255) & ~(size_t)255;
    return p;
  };
  const size_t big = (size_t)BT_ * C_ * 2;   // 16 MB
  const size_t wsz = (size_t)C_ * C_ * 2;    // 2 MB
  u16* qb  = (u16*)nxt(big);
  u16* kb  = (u16*)nxt(big);
  u16* vb  = (u16*)nxt(big);
  u16* Wqb = (u16*)nxt(wsz);
  u16* Wkb = (u16*)nxt(wsz);
  u16* Wvb = (u16*)nxt(wsz);
  u16* Wfb = (u16*)nxt(wsz);
  u16* Qh  = (u16*)nxt(big);
  u16* Kh  = (u16*)nxt(big);
  u16* Vt  = (u16*)nxt(big);
  u16* Yb  = (u16*)nxt(big);
  u64* mb  = (u64*)nxt((size_t)B_ * T_ * (T_ / 64) * 8);

  // conversions
  cvt_bf16_k<<<2048, 256, 0, stream>>>(q, qb, BT_ * C_);
  cvt_bf16_k<<<2048, 256, 0, stream>>>(k, kb, BT_ * C_);
  cvt_bf16_k<<<2048, 256, 0, stream>>>(v, vb, BT_ * C_);
  cvt_bf16_k<<<512, 256, 0, stream>>>(Wq, Wqb, C_ * C_);
  cvt_bf16_k<<<512, 256, 0, stream>>>(Wk, Wkb, C_ * C_);
  cvt_bf16_k<<<512, 256, 0, stream>>>(Wv, Wvb, C_ * C_);
  cvt_bf16_k<<<512, 256, 0, stream>>>(Wf, Wfb, C_ * C_);
  mask_bits_k<<<2048, 256, 0, stream>>>(mask, mb, B_ * T_ * T_ / 64);

  // projections: Q (scaled by 1/sqrt(dk)*log2e, folded into attention), K
  const float qscale = 0.125f * 1.4426950408889634f;
  gemm_nt<0><<<dim3(BT_ / 128, C_ / 128), 256, 0, stream>>>(qb, Wqb, bq, Qh, BT_, C_, C_, qscale);
  gemm_nt<0><<<dim3(BT_ / 128, C_ / 128), 256, 0, stream>>>(kb, Wkb, bk, Kh, BT_, C_, C_, 1.0f);
  // V transposed: Vt[h*64+d][b*T+t]  (A = Wv, B = vb)
  gemm_nt<1><<<dim3(C_ / 128, BT_ / 128), 256, 0, stream>>>(Wvb, vb, bv, Vt, C_, BT_, C_, 1.0f);

  // attention: 1024 blocks x 256 threads, no LDS
  attn32_k<<<B_ * H_ * (T_ / 128), 256, 0, stream>>>(Qh, Kh, Vt, mb, Yb);

  // output projection -> f32 d_out
  gemm_nt<2><<<dim3(BT_ / 128, C_ / 128), 256, 0, stream>>>(Yb, Wfb, bf, out, BT_, C_, C_, 1.0f);
}

// Round 4
// 330.400 us; speedup vs baseline: 2.1228x; 1.6457x over previous
//
#include <hip/hip_runtime.h>

#define B_ 4
#define T_ 2048
#define C_ 1024
#define H_ 16
#define DK_ 64
#define BT_ 8192

using u16 = unsigned short;
using u32 = unsigned int;
using u64 = unsigned long long;
typedef __attribute__((ext_vector_type(8))) short short8;
typedef __attribute__((ext_vector_type(4))) float f32x4;
typedef __attribute__((ext_vector_type(16))) float f32x16;
typedef __attribute__((ext_vector_type(4))) u32 u32x4;
typedef __attribute__((ext_vector_type(2))) u32 u32x2;

__device__ __forceinline__ u16 f2bf(float f) {
  u32 u = __builtin_bit_cast(u32, f);
  u32 r = u + 0x7fffu + ((u >> 16) & 1u);
  return (u16)(r >> 16);
}

__device__ __forceinline__ void glds16(void* lds, const void* g) {
  __builtin_amdgcn_global_load_lds(
      (__attribute__((address_space(1))) u32*)g,
      (__attribute__((address_space(3))) u32*)lds, 16, 0, 0);
}

// ---------------- fp32 -> bf16 conversion (vectorized, grid-stride) ---------
__global__ void cvt_bf16_k(const float* __restrict__ s, u16* __restrict__ d, int n) {
  int i0 = (blockIdx.x * blockDim.x + threadIdx.x) * 4;
  int stride = gridDim.x * blockDim.x * 4;
  for (int i = i0; i < n; i += stride) {
    float4 v = *(const float4*)(s + i);
    u64 p = (u64)f2bf(v.x) | ((u64)f2bf(v.y) << 16) |
            ((u64)f2bf(v.z) << 32) | ((u64)f2bf(v.w) << 48);
    *(u64*)(d + i) = p;
  }
}

// ---------------- mask int32 -> bitmask (1 bit per entry) -------------------
__global__ void mask_bits_k(const int* __restrict__ m, u64* __restrict__ out, int nw) {
  int w0 = blockIdx.x * (blockDim.x >> 6) + (threadIdx.x >> 6);
  int lane = threadIdx.x & 63;
  int stride = gridDim.x * (blockDim.x >> 6);
  for (int w = w0; w < nw; w += stride) {
    int v = m[(size_t)w * 64 + lane];
    u64 bits = __ballot(v != 0);
    if (lane == 0) out[w] = bits;
  }
}

// ---------------- NT GEMM, 128x128 tile, bf16 MFMA (m97 structure) ----------
template <int MODE>
__global__ __launch_bounds__(256) void gemm_nt(
    const u16* __restrict__ A, const u16* __restrict__ Bmat,
    const float* __restrict__ bias, void* __restrict__ out,
    int M, int N, int K, float scale) {
  __shared__ __align__(16) u16 As[128 * 32];
  __shared__ __align__(16) u16 Bs[128 * 32];
  const int t = threadIdx.x;
  const int lane = t & 63;
  const int wave = t >> 6;
  const int wr = wave >> 1, wc = wave & 1;
  const int lr = lane & 15, lg = lane >> 4;
  const int m0 = blockIdx.x * 128;
  const int n0 = blockIdx.y * 128;

  f32x4 acc[4][4] = {};

  const int srow = t >> 2;
  const int scol = (t & 3) * 8;
  const u16* ag = A + (size_t)(m0 + srow) * K + scol;
  const u16* bg = Bmat + (size_t)(n0 + srow) * K + scol;
  u16* as0 = &As[srow * 32 + scol];
  u16* as1 = &As[(srow + 64) * 32 + scol];
  u16* bs0 = &Bs[srow * 32 + scol];
  u16* bs1 = &Bs[(srow + 64) * 32 + scol];

  for (int k0 = 0; k0 < K; k0 += 32) {
    glds16(as0, ag + k0);
    glds16(as1, ag + (size_t)64 * K + k0);
    glds16(bs0, bg + k0);
    glds16(bs1, bg + (size_t)64 * K + k0);
    __syncthreads();
    short8 af[4], bf[4];
#pragma unroll
    for (int m = 0; m < 4; ++m)
      af[m] = *(const short8*)&As[(wr * 64 + m * 16 + lr) * 32 + lg * 8];
#pragma unroll
    for (int n = 0; n < 4; ++n)
      bf[n] = *(const short8*)&Bs[(wc * 64 + n * 16 + lr) * 32 + lg * 8];
#pragma unroll
    for (int m = 0; m < 4; ++m)
#pragma unroll
      for (int n = 0; n < 4; ++n)
        acc[m][n] = __builtin_amdgcn_mfma_f32_16x16x32_bf16(af[m], bf[n], acc[m][n], 0, 0, 0);
    __syncthreads();
  }

#pragma unroll
  for (int m = 0; m < 4; ++m) {
#pragma unroll
    for (int n = 0; n < 4; ++n) {
#pragma unroll
      for (int j = 0; j < 4; ++j) {
        const int gm = m0 + wr * 64 + m * 16 + lg * 4 + j;
        const int gn = n0 + wc * 64 + n * 16 + lr;
        float v = acc[m][n][j];
        if (MODE == 0) {
          v = (v + bias[gn]) * scale;
          const int b = gm >> 11, tt = gm & 2047, h = gn >> 6, d = gn & 63;
          ((u16*)out)[((((size_t)b * H_ + h) * T_ + tt) << 6) + d] = f2bf(v);
        } else if (MODE == 1) {
          v += bias[gm];
          ((u16*)out)[(size_t)gm * N + gn] = f2bf(v);
        } else {
          v += bias[gn];
          ((float*)out)[(size_t)gm * N + gn] = v;
        }
      }
    }
  }
}

// ---------------- masked flash attention, swapped-QK^T 32x32, LDS-staged ----
// Qh: [B,H,T,64] bf16, pre-scaled by 0.125*log2(e).  Kh: [B,H,T,64] bf16.
// Vt: [H*64][B*T] bf16.  mb: [B,T,T/64] bitmask.  Y: [B,T,C] bf16.
// 4 waves/block share K/V tiles via double-buffered LDS (global_load_lds w16),
// XOR swizzle col16 ^= row&7 applied on BOTH global source and LDS read.
__global__ __launch_bounds__(256) void attn32_k(
    const u16* __restrict__ Qh, const u16* __restrict__ Kh,
    const u16* __restrict__ Vt, const u64* __restrict__ mb,
    u16* __restrict__ Y) {
  __shared__ __align__(16) u16 Ks[2][64 * 64];
  __shared__ __align__(16) u16 Vs[2][64 * 64];

  // XCD-bijective remap: 1024 blocks, 128 consecutive logical ids per XCD
  const int f = blockIdx.x;
  const int lgid = ((f & 7) << 7) | (f >> 3);
  const int bh = lgid >> 4, qblk = lgid & 15;
  const int b = bh >> 4, h = bh & 15;
  const int t = threadIdx.x;
  const int wave = t >> 6, lane = t & 63;
  const int lq = lane & 31, hi = lane >> 5;
  const int q0 = qblk * 128 + wave * 32;

  // Q B-fragments: lane holds Q[q0+lq][kt*16 + 8*hi .. +7]
  const u16* Qp = Qh + ((size_t)bh * T_ + q0 + lq) * DK_ + hi * 8;
  short8 qf[4];
#pragma unroll
  for (int kt = 0; kt < 4; ++kt) qf[kt] = *(const short8*)(Qp + kt * 16);

  const u16* KgB = Kh + (size_t)bh * T_ * DK_;
  const u16* VtB = Vt + (size_t)h * DK_ * BT_ + (size_t)b * T_;  // + r*BT + kv
  const u64* mrow = mb + ((size_t)b * T_ + q0 + lq) * (T_ / 64);

  // stage K/V 64-kv tile into buf: chunk i (16B) -> row r=i>>3, lds col i&7,
  // global col (i&7)^(r&7). LDS dst linear per wave (glds requirement).
  auto stage = [&](int buf, int kv) {
#pragma unroll
    for (int s = 0; s < 2; ++s) {
      const int i = t + s * 256;
      const int r = i >> 3;
      const int c = (i & 7) ^ (r & 7);
      glds16(&Ks[buf][i * 8], KgB + (size_t)(kv + r) * DK_ + c * 8);
      glds16(&Vs[buf][i * 8], VtB + (size_t)r * BT_ + kv + c * 8);
    }
  };

  float m_run = -3.0e38f, l_run = 0.f;
  f32x16 o0 = {}, o1 = {};

  stage(0, 0);
  __syncthreads();
  int cur = 0;

  for (int kv = 0; kv < T_; kv += 64) {
    if (kv + 64 < T_) stage(cur ^ 1, kv + 64);

    const u64 mw = mrow[kv >> 6] >> (hi * 4);
    const u32 mlo = (u32)mw, mhi2 = (u32)(mw >> 32);

    // S^T = K * Q^T from swizzled LDS tile
    f32x16 c0 = {}, c1 = {};
    __builtin_amdgcn_s_setprio(1);
#pragma unroll
    for (int kt = 0; kt < 4; ++kt) {
      const int off16 = (kt * 2 + hi) ^ (lq & 7);
      const short8 k0 = *(const short8*)&Ks[cur][lq * 64 + off16 * 8];
      const short8 k1 = *(const short8*)&Ks[cur][(lq + 32) * 64 + off16 * 8];
      c0 = __builtin_amdgcn_mfma_f32_32x32x16_bf16(k0, qf[kt], c0, 0, 0, 0);
      c1 = __builtin_amdgcn_mfma_f32_32x32x16_bf16(k1, qf[kt], c1, 0, 0, 0);
    }
    __builtin_amdgcn_s_setprio(0);

    float s0[16], s1[16];
#pragma unroll
    for (int r = 0; r < 16; ++r) {
      const int pos = (r & 3) + 8 * (r >> 2);
      s0[r] = ((mlo >> pos) & 1u) ? c0[r] : -1e9f;
      s1[r] = ((mhi2 >> pos) & 1u) ? c1[r] : -1e9f;
    }
    float mx[8];
#pragma unroll
    for (int r = 0; r < 8; ++r)
      mx[r] = fmaxf(fmaxf(s0[r], s0[r + 8]), fmaxf(s1[r], s1[r + 8]));
#pragma unroll
    for (int d = 4; d; d >>= 1)
#pragma unroll
      for (int r = 0; r < d; ++r) mx[r] = fmaxf(mx[r], mx[r + d]);
    const float pmax = fmaxf(mx[0], __shfl_xor(mx[0], 32));

    if (!__all(pmax <= m_run + 8.0f)) {
      const float mnew = fmaxf(m_run, pmax);
      const float al = __builtin_amdgcn_exp2f(m_run - mnew);
      m_run = mnew;
      l_run *= al;
#pragma unroll
      for (int r = 0; r < 16; ++r) {
        const int row = (r & 3) + 8 * (r >> 2) + 4 * hi;
        const float alr = __shfl(al, row);
        o0[r] *= alr;
        o1[r] *= alr;
      }
    }

#pragma unroll
    for (int r = 0; r < 16; ++r) {
      s0[r] = __builtin_amdgcn_exp2f(s0[r] - m_run);
      s1[r] = __builtin_amdgcn_exp2f(s1[r] - m_run);
    }
    float sm[8];
#pragma unroll
    for (int r = 0; r < 8; ++r)
      sm[r] = (s0[r] + s0[r + 8]) + (s1[r] + s1[r + 8]);
#pragma unroll
    for (int d = 4; d; d >>= 1)
#pragma unroll
      for (int r = 0; r < d; ++r) sm[r] += sm[r + d];
    l_run += sm[0] + __shfl_xor(sm[0], 32);

    // P -> bf16 PV A-fragments, IN-LANE pack (relabeled contraction sigma)
    u32 pw_[4][4];
#pragma unroll
    for (int g = 0; g < 4; ++g) {
      const float* pe = (g < 2) ? s0 : s1;
      const int ob = (g & 1) * 8;
#pragma unroll
      for (int w2 = 0; w2 < 4; ++w2)
        pw_[g][w2] = (u32)f2bf(pe[ob + 2 * w2]) |
                     ((u32)f2bf(pe[ob + 2 * w2 + 1]) << 16);
    }
    __builtin_amdgcn_s_setprio(1);
#pragma unroll
    for (int g = 0; g < 4; ++g) {
      // V^T fragment rows lq (o0) / lq+32 (o1) from swizzled LDS:
      // element bytes in row: g*32 + hi*8 (+16) -> col16 = 2g (2g+1), rem hi*8
      const int cA = (2 * g) ^ (lq & 7);
      const int cB = (2 * g + 1) ^ (lq & 7);
      const u32x2 l0 = *(const u32x2*)&Vs[cur][lq * 64 + cA * 8 + hi * 4];
      const u32x2 l1 = *(const u32x2*)&Vs[cur][lq * 64 + cB * 8 + hi * 4];
      const u32x2 n0v = *(const u32x2*)&Vs[cur][(lq + 32) * 64 + cA * 8 + hi * 4];
      const u32x2 n1v = *(const u32x2*)&Vs[cur][(lq + 32) * 64 + cB * 8 + hi * 4];
      const u32x4 pu = {pw_[g][0], pw_[g][1], pw_[g][2], pw_[g][3]};
      const u32x4 v0u = {l0[0], l0[1], l1[0], l1[1]};
      const u32x4 v1u = {n0v[0], n0v[1], n1v[0], n1v[1]};
      const short8 pa = __builtin_bit_cast(short8, pu);
      o0 = __builtin_amdgcn_mfma_f32_32x32x16_bf16(pa, __builtin_bit_cast(short8, v0u), o0, 0, 0, 0);
      o1 = __builtin_amdgcn_mfma_f32_32x32x16_bf16(pa, __builtin_bit_cast(short8, v1u), o1, 0, 0, 0);
    }
    __builtin_amdgcn_s_setprio(0);

    __syncthreads();
    cur ^= 1;
  }

  const float linv = 1.0f / l_run;
#pragma unroll
  for (int r = 0; r < 16; ++r) {
    const int row = (r & 3) + 8 * (r >> 2) + 4 * hi;
    const float li = __shfl(linv, row);
    u16* yp = Y + ((size_t)b * T_ + q0 + row) * C_ + h * DK_ + lq;
    yp[0] = f2bf(o0[r] * li);
    yp[32] = f2bf(o1[r] * li);
  }
}

// ---------------------------------------------------------------------------
extern "C" void kernel_launch(void* const* d_in, const int* in_sizes, int n_in,
                              void* d_out, int out_size, void* d_ws, size_t ws_size,
                              hipStream_t stream) {
  const float* q  = (const float*)d_in[0];
  const float* k  = (const float*)d_in[1];
  const float* v  = (const float*)d_in[2];
  const int* mask = (const int*)d_in[3];
  const float* Wq = (const float*)d_in[4];
  const float* bq = (const float*)d_in[5];
  const float* Wk = (const float*)d_in[6];
  const float* bk = (const float*)d_in[7];
  const float* Wv = (const float*)d_in[8];
  const float* bv = (const float*)d_in[9];
  const float* Wf = (const float*)d_in[10];
  const float* bf = (const float*)d_in[11];
  float* out = (float*)d_out;
  char* ws = (char*)d_ws;

  size_t off = 0;
  auto nxt = [&](size_t bytes) -> void* {
    void* p = ws + off;
    off += (bytes + 255) & ~(size_t)255;
    return p;
  };
  const size_t big = (size_t)BT_ * C_ * 2;   // 16 MB
  const size_t wsz = (size_t)C_ * C_ * 2;    // 2 MB
  u16* qb  = (u16*)nxt(big);
  u16* kb  = (u16*)nxt(big);
  u16* vb  = (u16*)nxt(big);
  u16* Wqb = (u16*)nxt(wsz);
  u16* Wkb = (u16*)nxt(wsz);
  u16* Wvb = (u16*)nxt(wsz);
  u16* Wfb = (u16*)nxt(wsz);
  u16* Qh  = (u16*)nxt(big);
  u16* Kh  = (u16*)nxt(big);
  u16* Vt  = (u16*)nxt(big);
  u16* Yb  = (u16*)nxt(big);
  u64* mb  = (u64*)nxt((size_t)B_ * T_ * (T_ / 64) * 8);

  // conversions
  cvt_bf16_k<<<2048, 256, 0, stream>>>(q, qb, BT_ * C_);
  cvt_bf16_k<<<2048, 256, 0, stream>>>(k, kb, BT_ * C_);
  cvt_bf16_k<<<2048, 256, 0, stream>>>(v, vb, BT_ * C_);
  cvt_bf16_k<<<512, 256, 0, stream>>>(Wq, Wqb, C_ * C_);
  cvt_bf16_k<<<512, 256, 0, stream>>>(Wk, Wkb, C_ * C_);
  cvt_bf16_k<<<512, 256, 0, stream>>>(Wv, Wvb, C_ * C_);
  cvt_bf16_k<<<512, 256, 0, stream>>>(Wf, Wfb, C_ * C_);
  mask_bits_k<<<2048, 256, 0, stream>>>(mask, mb, B_ * T_ * T_ / 64);

  // projections: Q (scaled by 1/sqrt(dk)*log2e, folded into attention), K
  const float qscale = 0.125f * 1.4426950408889634f;
  gemm_nt<0><<<dim3(BT_ / 128, C_ / 128), 256, 0, stream>>>(qb, Wqb, bq, Qh, BT_, C_, C_, qscale);
  gemm_nt<0><<<dim3(BT_ / 128, C_ / 128), 256, 0, stream>>>(kb, Wkb, bk, Kh, BT_, C_, C_, 1.0f);
  // V transposed: Vt[h*64+d][b*T+t]  (A = Wv, B = vb)
  gemm_nt<1><<<dim3(C_ / 128, BT_ / 128), 256, 0, stream>>>(Wvb, vb, bv, Vt, C_, BT_, C_, 1.0f);

  // attention: 1024 blocks x 256 threads, LDS-staged K/V
  attn32_k<<<B_ * H_ * (T_ / 128), 256, 0, stream>>>(Qh, Kh, Vt, mb, Yb);

  // output projection -> f32 d_out
  gemm_nt<2><<<dim3(BT_ / 128, C_ / 128), 256, 0, stream>>>(Yb, Wfb, bf, out, BT_, C_, C_, 1.0f);
}